// Round 3
// baseline (547.285 us; speedup 1.0000x reference)
//
#include <hip/hip_runtime.h>
#include <hip/hip_bf16.h>
#include <cstdint>
#include <cstddef>

#define T_TOK 2048
#define DIM   1024
#define FDIM  2048
#define NEXP  8

#define GU_MAX 48   // sum ceil(cnt/128) <= 24 routed + 16 shared
#define DN_MAX 96   // <= 24 routed tiles * 4 K-chunks

typedef short  short8  __attribute__((ext_vector_type(8)));
typedef float  floatx4 __attribute__((ext_vector_type(4)));

__device__ inline unsigned short f2bf(float f) {
    unsigned int u = __builtin_bit_cast(unsigned int, f);
    unsigned int r = (u + 0x7FFFu + ((u >> 16) & 1u)) >> 16;  // RNE
    return (unsigned short)r;
}

// v_cvt_pk_bf16_f32: lo=bf16(a), hi=bf16(b). Hardware RNE on gfx950.
__device__ inline unsigned int cvtpk(float a, float b) {
    unsigned int r;
    asm("v_cvt_pk_bf16_f32 %0, %1, %2" : "=v"(r) : "v"(a), "v"(b));
    return r;
}

// async global->LDS 16B/lane; lds base MUST be wave-uniform (HW: base + lane*16)
__device__ inline void glds16(const void* g, const unsigned short* lds_base, int elem_off) {
    int u = __builtin_amdgcn_readfirstlane(elem_off);  // force SGPR: no waterfall
    __builtin_amdgcn_global_load_lds(
        (const __attribute__((address_space(1))) unsigned int*)g,
        (__attribute__((address_space(3))) unsigned int*)(lds_base + u), 16, 0, 0);
}

// ---------------- Kernel: router + bf16 activation prep ----------------
__global__ __launch_bounds__(256) void k_router(
    const float* __restrict__ h, const float* __restrict__ rw,
    int* __restrict__ counts, int* __restrict__ lists,
    unsigned short* __restrict__ hb, unsigned short* __restrict__ xb)
{
    int w = threadIdx.x >> 6, lane = threadIdx.x & 63;
    int t = blockIdx.x * 4 + w;
    const float* hrow = h + (size_t)t * DIM;
    float hv[16];
    #pragma unroll
    for (int i = 0; i < 16; ++i) hv[i] = hrow[lane + 64 * i];
    float acc[NEXP];
    #pragma unroll
    for (int e = 0; e < NEXP; ++e) {
        const float* r = rw + (size_t)e * DIM;
        float s = 0.f;
        #pragma unroll
        for (int i = 0; i < 16; ++i) s += hv[i] * r[lane + 64 * i];
        acc[e] = s;
    }
    #pragma unroll
    for (int e = 0; e < NEXP; ++e) {
        float s = acc[e];
        for (int off = 32; off > 0; off >>= 1) s += __shfl_down(s, off);
        acc[e] = s;
    }
    float score = 0.f;
    if (lane == 0) {
        int be = 0; float bv = acc[0];
        #pragma unroll
        for (int e = 1; e < NEXP; ++e) if (acc[e] > bv) { bv = acc[e]; be = e; }
        score = 1.f / (1.f + __expf(-bv));
        int pos = atomicAdd(&counts[be], 1);
        lists[be * T_TOK + pos] = t;
    }
    score = __shfl(score, 0);
    unsigned short* hbr = hb + (size_t)t * DIM;
    unsigned short* xbr = xb + (size_t)t * DIM;
    #pragma unroll
    for (int i = 0; i < 16; ++i) {
        hbr[lane + 64 * i] = f2bf(hv[i]);
        xbr[lane + 64 * i] = f2bf(score * hv[i]);
    }
}

// ---------------- Kernel: compact tile scheduler (128-row tiles) --------
__global__ void k_schedule(const int* __restrict__ counts,
                           int* __restrict__ gu, int* __restrict__ dn)
{
    if (threadIdx.x != 0 || blockIdx.x != 0) return;
    int n = 0;
    for (int e = 0; e < NEXP; ++e) {
        int c = counts[e];
        for (int r = 0; r < c; r += 128) gu[n++] = (e << 16) | r;
    }
    for (int r = 0; r < T_TOK; r += 128) gu[n++] = (NEXP << 16) | r;
    while (n < GU_MAX) gu[n++] = -1;
    n = 0;
    for (int e = 0; e < NEXP; ++e) {
        int c = counts[e];
        for (int r = 0; r < c; r += 128)
            for (int kc = 0; kc < 4; ++kc)         // (half = kc>>1, chunk = kc&1)
                dn[n++] = (kc << 26) | (e << 16) | r;
    }
    while (n < DN_MAX) dn[n++] = -1;
}

// ---------------- Kernel: fused gate/up GEMM + silu*mul -> Hc ----------
// 128x64 tile (1024 valid blocks -> ~4/CU, inter-block latency overlap),
// K=1024, BK=32. Counted-vmcnt pipeline: s_waitcnt vmcnt(16) at the raw
// barrier retires the 2 glds16 of tile t while the 16 B-prefetch loads of
// tile t+1 stay in flight across the barrier. LDS conflict evidence
// (r1: count == 18.0 * #glds16 exactly) says A/B layouts are clean.
__global__ __launch_bounds__(256, 4) void k_gateup(
    const unsigned short* __restrict__ xb, const unsigned short* __restrict__ hb,
    const float* __restrict__ w_gate, const float* __restrict__ w_up,
    const float* __restrict__ ws_gate, const float* __restrict__ ws_up,
    const int* __restrict__ counts, const int* __restrict__ lists,
    const int* __restrict__ gu_tiles, unsigned short* __restrict__ Hc)
{
    int ent = gu_tiles[blockIdx.y];
    if (ent < 0) return;
    int e = ent >> 16, row0 = ent & 0xffff;
    bool sh = (e == NEXP);
    int cnt = sh ? T_TOK : counts[e];
    const unsigned short* Asrc = sh ? hb : xb;
    const float* Bg = sh ? ws_gate : w_gate + (size_t)e * DIM * FDIM;
    const float* Bu = sh ? ws_up   : w_up   + (size_t)e * DIM * FDIM;
    int outoff = sh ? FDIM : 0;
    int col0 = blockIdx.x * 64;

    __shared__ int toks[128];
    __shared__ __align__(16) unsigned short As [2][128 * 32];
    __shared__ __align__(16) unsigned short Bgs[2][64 * 32];
    __shared__ __align__(16) unsigned short Bus[2][64 * 32];

    int tid = threadIdx.x;
    if (tid < 128) {
        int r = row0 + tid;
        toks[tid] = (r < cnt) ? (sh ? r : lists[e * T_TOK + r]) : -1;
    }
    __syncthreads();

    int lane = tid & 63, w = tid >> 6;

    // A staging: 2 rounds of glds16; global granule XOR-swizzled per row
    size_t agoff[2]; int albase[2];
    #pragma unroll
    for (int it = 0; it < 2; ++it) {
        int tt = tid + it * 256;
        int rr = tt >> 2, sq = tt & 3;
        int kg = (sq ^ ((rr >> 1) & 3)) * 8;
        int tk = toks[rr]; if (tk < 0) tk = 0;
        agoff[it] = (size_t)tk * DIM + kg;
        albase[it] = (it * 256 + w * 64) * 8;   // wave-uniform short offset
    }

    // B staging: thread owns one col c, k-octet kq = wave id.
    // Scalar loads: per instr 64 lanes read 256B contiguous (row k of panel).
    int c = tid & 63;
    int slotW = (w ^ ((c >> 1) & 3)) * 8;       // same XOR key as frag reads
    const float* bgp = Bg + (size_t)(w * 8) * FDIM + col0 + c;
    const float* bup = Bu + (size_t)(w * 8) * FDIM + col0 + c;

    float gx[8], ux[8];
    auto loadB = [&](int k0) {
        const float* pg = bgp + (size_t)k0 * FDIM;
        const float* pu = bup + (size_t)k0 * FDIM;
        #pragma unroll
        for (int j = 0; j < 8; ++j) {
            gx[j] = pg[(size_t)j * FDIM];
            ux[j] = pu[(size_t)j * FDIM];
        }
    };
    auto commitB = [&](int p_) {
        unsigned int gw[4], uw[4];
        #pragma unroll
        for (int j = 0; j < 4; ++j) {
            gw[j] = cvtpk(gx[2*j], gx[2*j+1]);
            uw[j] = cvtpk(ux[2*j], ux[2*j+1]);
        }
        *(uint4*)&Bgs[p_][c * 32 + slotW] = make_uint4(gw[0], gw[1], gw[2], gw[3]);
        *(uint4*)&Bus[p_][c * 32 + slotW] = make_uint4(uw[0], uw[1], uw[2], uw[3]);
    };
    auto loadA = [&](int k0, int p_) {
        #pragma unroll
        for (int it = 0; it < 2; ++it)
            glds16(Asrc + agoff[it] + k0, &As[p_][0], albase[it]);
    };

    floatx4 accg[2][4], accu[2][4];
    #pragma unroll
    for (int mi = 0; mi < 2; ++mi)
    #pragma unroll
    for (int ni = 0; ni < 4; ++ni) {
        floatx4 z = {0.f, 0.f, 0.f, 0.f};
        accg[mi][ni] = z; accu[mi][ni] = z;
    }

    // prologue: buf0 <- tile 0 (A async + B through regs); regs <- tile 1
    loadA(0, 0);
    loadB(0);
    commitB(0);      // compiler drains vmcnt here: tile0 fully staged
    loadB(32);       // 16 loads in flight entering the loop

    int p = 0;
    for (int k0 = 0; k0 < DIM; k0 += 32) {
        // steady state outstanding: stageA(t)[2 glds16] + loadB(t+1)[16].
        // vmcnt(16) retires exactly the A stage; B prefetch stays in flight.
        asm volatile("s_waitcnt vmcnt(16) lgkmcnt(0)\n\ts_barrier" ::: "memory");
        bool more = (k0 + 32 < DIM);
        if (more) loadA(k0 + 32, p ^ 1);
        __builtin_amdgcn_sched_barrier(0);   // pin glds16 before loadB (vmcnt order)
        int g = lane >> 4;
        short8 af[2], bgf[4], buf_[4];
        #pragma unroll
        for (int mi = 0; mi < 2; ++mi) {
            int r = w * 32 + mi * 16 + (lane & 15);
            int slot = (g ^ ((r >> 1) & 3)) * 8;
            af[mi] = *(const short8*)&As[p][r * 32 + slot];
        }
        #pragma unroll
        for (int ni = 0; ni < 4; ++ni) {
            int n = ni * 16 + (lane & 15);
            int slot = (g ^ ((n >> 1) & 3)) * 8;
            bgf[ni]  = *(const short8*)&Bgs[p][n * 32 + slot];
            buf_[ni] = *(const short8*)&Bus[p][n * 32 + slot];
        }
        if (more) {
            commitB(p ^ 1);          // compiler waits vmcnt(2): glds16 keeps flying
            int nk2 = k0 + 64; if (nk2 >= DIM) nk2 = 0;
            loadB(nk2);
        }
        __builtin_amdgcn_s_setprio(1);
        #pragma unroll
        for (int mi = 0; mi < 2; ++mi)
        #pragma unroll
        for (int ni = 0; ni < 4; ++ni) {
            accg[mi][ni] = __builtin_amdgcn_mfma_f32_16x16x32_bf16(af[mi], bgf[ni],  accg[mi][ni], 0, 0, 0);
            accu[mi][ni] = __builtin_amdgcn_mfma_f32_16x16x32_bf16(af[mi], buf_[ni], accu[mi][ni], 0, 0, 0);
        }
        __builtin_amdgcn_s_setprio(0);
        p ^= 1;
    }

    #pragma unroll
    for (int mi = 0; mi < 2; ++mi)
    #pragma unroll
    for (int ni = 0; ni < 4; ++ni)
    #pragma unroll
    for (int r = 0; r < 4; ++r) {
        int row = w * 32 + mi * 16 + (lane >> 4) * 4 + r;
        int tok = toks[row];
        if (tok < 0) continue;
        int col = col0 + ni * 16 + (lane & 15);
        float gv = accg[mi][ni][r], uv = accu[mi][ni][r];
        float hval = (gv / (1.f + __expf(-gv))) * uv;
        Hc[(size_t)tok * (2 * FDIM) + outoff + col] = f2bf(hval);
    }
}

// ---------------- Kernel: fused down-proj, split-K=4, atomic -----------
// 128x64 tile, K-chunk=1024 (2 halves x 2 chunks), BK=32; same pipeline.
// ~1024 valid blocks -> 4-6/CU resident.
__global__ __launch_bounds__(256, 4) void k_down(
    const unsigned short* __restrict__ Hc,
    const float* __restrict__ w_down, const float* __restrict__ ws_down,
    const int* __restrict__ counts, const int* __restrict__ lists,
    const int* __restrict__ dn_tiles, float* __restrict__ out)
{
    int ent = dn_tiles[blockIdx.y];
    if (ent < 0) return;
    int kc = (ent >> 26) & 3, e = (ent >> 16) & 0xff, row0 = ent & 0xffff;
    int half = kc >> 1, chunk = kc & 1;
    int cnt = counts[e];
    const float* B = (half ? ws_down : w_down + (size_t)e * FDIM * DIM)
                     + (size_t)(chunk * 1024) * DIM;
    int col0 = blockIdx.x * 64;
    size_t abase = (size_t)(half * FDIM + chunk * 1024);

    __shared__ int toks[128];
    __shared__ __align__(16) unsigned short As[2][128 * 32];
    __shared__ __align__(16) unsigned short Bs[2][64 * 32];

    int tid = threadIdx.x;
    if (tid < 128) {
        int r = row0 + tid;
        toks[tid] = (r < cnt) ? lists[e * T_TOK + r] : -1;
    }
    __syncthreads();

    int lane = tid & 63, w = tid >> 6;

    size_t agoff[2]; int albase[2];
    #pragma unroll
    for (int it = 0; it < 2; ++it) {
        int tt = tid + it * 256;
        int rr = tt >> 2, sq = tt & 3;
        int kg = (sq ^ ((rr >> 1) & 3)) * 8;
        int tk = toks[rr]; if (tk < 0) tk = 0;
        agoff[it] = (size_t)tk * (2 * FDIM) + abase + kg;
        albase[it] = (it * 256 + w * 64) * 8;
    }

    int c = tid & 63;
    int slotW = (w ^ ((c >> 1) & 3)) * 8;
    const float* bp_ = B + (size_t)(w * 8) * DIM + col0 + c;

    float bx[8];
    auto loadB = [&](int k0) {
        const float* pb = bp_ + (size_t)k0 * DIM;
        #pragma unroll
        for (int j = 0; j < 8; ++j) bx[j] = pb[(size_t)j * DIM];
    };
    auto commitB = [&](int p_) {
        unsigned int bw[4];
        #pragma unroll
        for (int j = 0; j < 4; ++j) bw[j] = cvtpk(bx[2*j], bx[2*j+1]);
        *(uint4*)&Bs[p_][c * 32 + slotW] = make_uint4(bw[0], bw[1], bw[2], bw[3]);
    };
    auto loadA = [&](int k0, int p_) {
        #pragma unroll
        for (int it = 0; it < 2; ++it)
            glds16(Hc + agoff[it] + k0, &As[p_][0], albase[it]);
    };

    floatx4 acc[2][4];
    #pragma unroll
    for (int mi = 0; mi < 2; ++mi)
    #pragma unroll
    for (int ni = 0; ni < 4; ++ni) {
        floatx4 z = {0.f, 0.f, 0.f, 0.f};
        acc[mi][ni] = z;
    }

    loadA(0, 0);
    loadB(0);
    commitB(0);
    loadB(32);

    int p = 0;
    for (int k0 = 0; k0 < 1024; k0 += 32) {
        // outstanding at top: stageA(t)[2] + loadB(t+1)[8] -> vmcnt(8)
        asm volatile("s_waitcnt vmcnt(8) lgkmcnt(0)\n\ts_barrier" ::: "memory");
        bool more = (k0 + 32 < 1024);
        if (more) loadA(k0 + 32, p ^ 1);
        __builtin_amdgcn_sched_barrier(0);
        int g = lane >> 4;
        short8 af[2], bf[4];
        #pragma unroll
        for (int mi = 0; mi < 2; ++mi) {
            int r = w * 32 + mi * 16 + (lane & 15);
            int slot = (g ^ ((r >> 1) & 3)) * 8;
            af[mi] = *(const short8*)&As[p][r * 32 + slot];
        }
        #pragma unroll
        for (int ni = 0; ni < 4; ++ni) {
            int n = ni * 16 + (lane & 15);
            int slot = (g ^ ((n >> 1) & 3)) * 8;
            bf[ni] = *(const short8*)&Bs[p][n * 32 + slot];
        }
        if (more) {
            commitB(p ^ 1);
            int nk2 = k0 + 64; if (nk2 >= 1024) nk2 = 0;
            loadB(nk2);
        }
        __builtin_amdgcn_s_setprio(1);
        #pragma unroll
        for (int mi = 0; mi < 2; ++mi)
        #pragma unroll
        for (int ni = 0; ni < 4; ++ni)
            acc[mi][ni] = __builtin_amdgcn_mfma_f32_16x16x32_bf16(af[mi], bf[ni], acc[mi][ni], 0, 0, 0);
        __builtin_amdgcn_s_setprio(0);
        p ^= 1;
    }

    #pragma unroll
    for (int mi = 0; mi < 2; ++mi)
    #pragma unroll
    for (int ni = 0; ni < 4; ++ni)
    #pragma unroll
    for (int r = 0; r < 4; ++r) {
        int row = w * 32 + mi * 16 + (lane >> 4) * 4 + r;
        int tok = toks[row];
        if (tok < 0) continue;
        int col = col0 + ni * 16 + (lane & 15);
        atomicAdd(&out[(size_t)tok * DIM + col], acc[mi][ni][r]);
    }
}

extern "C" void kernel_launch(void* const* d_in, const int* in_sizes, int n_in,
                              void* d_out, int out_size, void* d_ws, size_t ws_size,
                              hipStream_t stream)
{
    const float* h   = (const float*)d_in[0];
    const float* rw  = (const float*)d_in[1];
    const float* wg  = (const float*)d_in[2];
    const float* wu  = (const float*)d_in[3];
    const float* wd  = (const float*)d_in[4];
    const float* wsg = (const float*)d_in[5];
    const float* wsu = (const float*)d_in[6];
    const float* wsd = (const float*)d_in[7];
    float* out = (float*)d_out;

    char* ws = (char*)d_ws;
    int* counts   = (int*)ws;
    int* gu_tiles = (int*)(ws + 256);
    int* dn_tiles = (int*)(ws + 1024);
    int* lists    = (int*)(ws + 2048);                        // 64 KB
    unsigned short* hb = (unsigned short*)(ws + 131072);      // [T][D] bf16, 4 MB
    unsigned short* xb = hb + (size_t)T_TOK * DIM;            // 4 MB
    unsigned short* Hc = xb + (size_t)T_TOK * DIM;            // [T][2F] bf16, 16 MB

    (void)hipMemsetAsync(counts, 0, 64, stream);
    (void)hipMemsetAsync(out, 0, (size_t)T_TOK * DIM * sizeof(float), stream);
    k_router<<<dim3(T_TOK / 4), 256, 0, stream>>>(h, rw, counts, lists, hb, xb);
    k_schedule<<<dim3(1), 64, 0, stream>>>(counts, gu_tiles, dn_tiles);
    k_gateup<<<dim3(FDIM / 64, GU_MAX), 256, 0, stream>>>(
        xb, hb, wg, wu, wsg, wsu, counts, lists, gu_tiles, Hc);
    k_down<<<dim3(DIM / 64, DN_MAX), 256, 0, stream>>>(
        Hc, wd, wsd, counts, lists, dn_tiles, out);
}

// Round 4
// 372.927 us; speedup vs baseline: 1.4675x; 1.4675x over previous
//
#include <hip/hip_runtime.h>
#include <hip/hip_bf16.h>
#include <cstdint>
#include <cstddef>

#define T_TOK 2048
#define DIM   1024
#define FDIM  2048
#define NEXP  8

#define GU_MAX 48   // sum ceil(cnt/128) <= 24 routed + 16 shared
#define DN_MAX 96   // <= 24 routed tiles * 4 K-chunks

typedef short  short8  __attribute__((ext_vector_type(8)));
typedef float  floatx4 __attribute__((ext_vector_type(4)));

__device__ inline unsigned short f2bf(float f) {
    unsigned int u = __builtin_bit_cast(unsigned int, f);
    unsigned int r = (u + 0x7FFFu + ((u >> 16) & 1u)) >> 16;  // RNE
    return (unsigned short)r;
}

// v_cvt_pk_bf16_f32: lo=bf16(a), hi=bf16(b). Hardware RNE on gfx950.
__device__ inline unsigned int cvtpk(float a, float b) {
    unsigned int r;
    asm("v_cvt_pk_bf16_f32 %0, %1, %2" : "=v"(r) : "v"(a), "v"(b));
    return r;
}

// async global->LDS 16B/lane; lds base MUST be wave-uniform (HW: base + lane*16)
__device__ inline void glds16(const void* g, const unsigned short* lds_base, int elem_off) {
    int u = __builtin_amdgcn_readfirstlane(elem_off);  // force SGPR: no waterfall
    __builtin_amdgcn_global_load_lds(
        (const __attribute__((address_space(1))) unsigned int*)g,
        (__attribute__((address_space(3))) unsigned int*)(lds_base + u), 16, 0, 0);
}

// ---------------- Kernel: router + bf16 activation prep ----------------
__global__ __launch_bounds__(256) void k_router(
    const float* __restrict__ h, const float* __restrict__ rw,
    int* __restrict__ counts, int* __restrict__ lists,
    unsigned short* __restrict__ hb, unsigned short* __restrict__ xb)
{
    int w = threadIdx.x >> 6, lane = threadIdx.x & 63;
    int t = blockIdx.x * 4 + w;
    const float* hrow = h + (size_t)t * DIM;
    float hv[16];
    #pragma unroll
    for (int i = 0; i < 16; ++i) hv[i] = hrow[lane + 64 * i];
    float acc[NEXP];
    #pragma unroll
    for (int e = 0; e < NEXP; ++e) {
        const float* r = rw + (size_t)e * DIM;
        float s = 0.f;
        #pragma unroll
        for (int i = 0; i < 16; ++i) s += hv[i] * r[lane + 64 * i];
        acc[e] = s;
    }
    #pragma unroll
    for (int e = 0; e < NEXP; ++e) {
        float s = acc[e];
        for (int off = 32; off > 0; off >>= 1) s += __shfl_down(s, off);
        acc[e] = s;
    }
    float score = 0.f;
    if (lane == 0) {
        int be = 0; float bv = acc[0];
        #pragma unroll
        for (int e = 1; e < NEXP; ++e) if (acc[e] > bv) { bv = acc[e]; be = e; }
        score = 1.f / (1.f + __expf(-bv));
        int pos = atomicAdd(&counts[be], 1);
        lists[be * T_TOK + pos] = t;
    }
    score = __shfl(score, 0);
    unsigned short* hbr = hb + (size_t)t * DIM;
    unsigned short* xbr = xb + (size_t)t * DIM;
    #pragma unroll
    for (int i = 0; i < 16; ++i) {
        hbr[lane + 64 * i] = f2bf(hv[i]);
        xbr[lane + 64 * i] = f2bf(score * hv[i]);
    }
}

// ---------------- Kernel: compact tile scheduler (128-row tiles) --------
__global__ void k_schedule(const int* __restrict__ counts,
                           int* __restrict__ gu, int* __restrict__ dn)
{
    if (threadIdx.x != 0 || blockIdx.x != 0) return;
    int n = 0;
    for (int e = 0; e < NEXP; ++e) {
        int c = counts[e];
        for (int r = 0; r < c; r += 128) gu[n++] = (e << 16) | r;
    }
    for (int r = 0; r < T_TOK; r += 128) gu[n++] = (NEXP << 16) | r;
    while (n < GU_MAX) gu[n++] = -1;
    n = 0;
    for (int e = 0; e < NEXP; ++e) {
        int c = counts[e];
        for (int r = 0; r < c; r += 128)
            for (int kc = 0; kc < 4; ++kc)         // (half = kc>>1, chunk = kc&1)
                dn[n++] = (kc << 26) | (e << 16) | r;
    }
    while (n < DN_MAX) dn[n++] = -1;
}

// ---------------- Kernel: fused gate/up GEMM + silu*mul -> Hc ----------
// 128x64 tile (1280 valid blocks), K=1024, BK=32. Counted-vmcnt pipeline:
// s_waitcnt vmcnt(16) at the raw barrier retires the 2 glds16 of tile t
// while the 16 B-prefetch loads of tile t+1 stay in flight.
// launch_bounds(256,2): natural regalloc (~155 unified) -> NO scratch
// spill (r3 post-mortem: (256,4) forced 128-reg cap -> 266 MB spill
// traffic, MfmaUtil 5%). 3 blocks/CU from VGPR, LDS 33 KB allows 4.
// r3 also proved this LDS layout is conflict-free (SQ_LDS_BANK_CONFLICT=0).
__global__ __launch_bounds__(256, 2) void k_gateup(
    const unsigned short* __restrict__ xb, const unsigned short* __restrict__ hb,
    const float* __restrict__ w_gate, const float* __restrict__ w_up,
    const float* __restrict__ ws_gate, const float* __restrict__ ws_up,
    const int* __restrict__ counts, const int* __restrict__ lists,
    const int* __restrict__ gu_tiles, unsigned short* __restrict__ Hc)
{
    int ent = gu_tiles[blockIdx.y];
    if (ent < 0) return;
    int e = ent >> 16, row0 = ent & 0xffff;
    bool sh = (e == NEXP);
    int cnt = sh ? T_TOK : counts[e];
    const unsigned short* Asrc = sh ? hb : xb;
    const float* Bg = sh ? ws_gate : w_gate + (size_t)e * DIM * FDIM;
    const float* Bu = sh ? ws_up   : w_up   + (size_t)e * DIM * FDIM;
    int outoff = sh ? FDIM : 0;
    int col0 = blockIdx.x * 64;

    __shared__ int toks[128];
    __shared__ __align__(16) unsigned short As [2][128 * 32];
    __shared__ __align__(16) unsigned short Bgs[2][64 * 32];
    __shared__ __align__(16) unsigned short Bus[2][64 * 32];

    int tid = threadIdx.x;
    if (tid < 128) {
        int r = row0 + tid;
        toks[tid] = (r < cnt) ? (sh ? r : lists[e * T_TOK + r]) : -1;
    }
    __syncthreads();

    int lane = tid & 63, w = tid >> 6;

    // A staging: 2 rounds of glds16; global granule XOR-swizzled per row
    size_t agoff[2]; int albase[2];
    #pragma unroll
    for (int it = 0; it < 2; ++it) {
        int tt = tid + it * 256;
        int rr = tt >> 2, sq = tt & 3;
        int kg = (sq ^ ((rr >> 1) & 3)) * 8;
        int tk = toks[rr]; if (tk < 0) tk = 0;
        agoff[it] = (size_t)tk * DIM + kg;
        albase[it] = (it * 256 + w * 64) * 8;   // wave-uniform short offset
    }

    // B staging: thread owns one col c, k-octet kq = wave id.
    // Scalar loads: per instr 64 lanes read 256B contiguous (row k of panel).
    int c = tid & 63;
    int slotW = (w ^ ((c >> 1) & 3)) * 8;       // same XOR key as frag reads
    const float* bgp = Bg + (size_t)(w * 8) * FDIM + col0 + c;
    const float* bup = Bu + (size_t)(w * 8) * FDIM + col0 + c;

    float gx[8], ux[8];
    auto loadB = [&](int k0) {
        const float* pg = bgp + (size_t)k0 * FDIM;
        const float* pu = bup + (size_t)k0 * FDIM;
        #pragma unroll
        for (int j = 0; j < 8; ++j) {
            gx[j] = pg[(size_t)j * FDIM];
            ux[j] = pu[(size_t)j * FDIM];
        }
    };
    auto commitB = [&](int p_) {
        unsigned int gw[4], uw[4];
        #pragma unroll
        for (int j = 0; j < 4; ++j) {
            gw[j] = cvtpk(gx[2*j], gx[2*j+1]);
            uw[j] = cvtpk(ux[2*j], ux[2*j+1]);
        }
        *(uint4*)&Bgs[p_][c * 32 + slotW] = make_uint4(gw[0], gw[1], gw[2], gw[3]);
        *(uint4*)&Bus[p_][c * 32 + slotW] = make_uint4(uw[0], uw[1], uw[2], uw[3]);
    };
    auto loadA = [&](int k0, int p_) {
        #pragma unroll
        for (int it = 0; it < 2; ++it)
            glds16(Asrc + agoff[it] + k0, &As[p_][0], albase[it]);
    };

    floatx4 accg[2][4], accu[2][4];
    #pragma unroll
    for (int mi = 0; mi < 2; ++mi)
    #pragma unroll
    for (int ni = 0; ni < 4; ++ni) {
        floatx4 z = {0.f, 0.f, 0.f, 0.f};
        accg[mi][ni] = z; accu[mi][ni] = z;
    }

    // prologue: buf0 <- tile 0 (A async + B through regs); regs <- tile 1
    loadA(0, 0);
    loadB(0);
    commitB(0);      // compiler drains vmcnt here: tile0 fully staged
    loadB(32);       // 16 loads in flight entering the loop

    int p = 0;
    for (int k0 = 0; k0 < DIM; k0 += 32) {
        // steady state outstanding: stageA(t)[2 glds16] + loadB(t+1)[16].
        // vmcnt(16) retires exactly the A stage; B prefetch stays in flight.
        asm volatile("s_waitcnt vmcnt(16) lgkmcnt(0)\n\ts_barrier" ::: "memory");
        bool more = (k0 + 32 < DIM);
        if (more) loadA(k0 + 32, p ^ 1);
        __builtin_amdgcn_sched_barrier(0);   // pin glds16 before loadB (vmcnt order)
        int g = lane >> 4;
        short8 af[2], bgf[4], buf_[4];
        #pragma unroll
        for (int mi = 0; mi < 2; ++mi) {
            int r = w * 32 + mi * 16 + (lane & 15);
            int slot = (g ^ ((r >> 1) & 3)) * 8;
            af[mi] = *(const short8*)&As[p][r * 32 + slot];
        }
        #pragma unroll
        for (int ni = 0; ni < 4; ++ni) {
            int n = ni * 16 + (lane & 15);
            int slot = (g ^ ((n >> 1) & 3)) * 8;
            bgf[ni]  = *(const short8*)&Bgs[p][n * 32 + slot];
            buf_[ni] = *(const short8*)&Bus[p][n * 32 + slot];
        }
        if (more) {
            commitB(p ^ 1);          // compiler waits vmcnt(2): glds16 keeps flying
            int nk2 = k0 + 64; if (nk2 >= DIM) nk2 = 0;
            loadB(nk2);
        }
        __builtin_amdgcn_s_setprio(1);
        #pragma unroll
        for (int mi = 0; mi < 2; ++mi)
        #pragma unroll
        for (int ni = 0; ni < 4; ++ni) {
            accg[mi][ni] = __builtin_amdgcn_mfma_f32_16x16x32_bf16(af[mi], bgf[ni],  accg[mi][ni], 0, 0, 0);
            accu[mi][ni] = __builtin_amdgcn_mfma_f32_16x16x32_bf16(af[mi], buf_[ni], accu[mi][ni], 0, 0, 0);
        }
        __builtin_amdgcn_s_setprio(0);
        p ^= 1;
    }

    #pragma unroll
    for (int mi = 0; mi < 2; ++mi)
    #pragma unroll
    for (int ni = 0; ni < 4; ++ni)
    #pragma unroll
    for (int r = 0; r < 4; ++r) {
        int row = w * 32 + mi * 16 + (lane >> 4) * 4 + r;
        int tok = toks[row];
        if (tok < 0) continue;
        int col = col0 + ni * 16 + (lane & 15);
        float gv = accg[mi][ni][r], uv = accu[mi][ni][r];
        float hval = (gv / (1.f + __expf(-gv))) * uv;
        Hc[(size_t)tok * (2 * FDIM) + outoff + col] = f2bf(hval);
    }
}

// ---------------- Kernel: fused down-proj, split-K=4, atomic -----------
// 128x64 tile, K-chunk=1024 (2 halves x 2 chunks), BK=32; same pipeline.
// launch_bounds(256,2): natural regalloc, no forced spill.
__global__ __launch_bounds__(256, 2) void k_down(
    const unsigned short* __restrict__ Hc,
    const float* __restrict__ w_down, const float* __restrict__ ws_down,
    const int* __restrict__ counts, const int* __restrict__ lists,
    const int* __restrict__ dn_tiles, float* __restrict__ out)
{
    int ent = dn_tiles[blockIdx.y];
    if (ent < 0) return;
    int kc = (ent >> 26) & 3, e = (ent >> 16) & 0xff, row0 = ent & 0xffff;
    int half = kc >> 1, chunk = kc & 1;
    int cnt = counts[e];
    const float* B = (half ? ws_down : w_down + (size_t)e * FDIM * DIM)
                     + (size_t)(chunk * 1024) * DIM;
    int col0 = blockIdx.x * 64;
    size_t abase = (size_t)(half * FDIM + chunk * 1024);

    __shared__ int toks[128];
    __shared__ __align__(16) unsigned short As[2][128 * 32];
    __shared__ __align__(16) unsigned short Bs[2][64 * 32];

    int tid = threadIdx.x;
    if (tid < 128) {
        int r = row0 + tid;
        toks[tid] = (r < cnt) ? lists[e * T_TOK + r] : -1;
    }
    __syncthreads();

    int lane = tid & 63, w = tid >> 6;

    size_t agoff[2]; int albase[2];
    #pragma unroll
    for (int it = 0; it < 2; ++it) {
        int tt = tid + it * 256;
        int rr = tt >> 2, sq = tt & 3;
        int kg = (sq ^ ((rr >> 1) & 3)) * 8;
        int tk = toks[rr]; if (tk < 0) tk = 0;
        agoff[it] = (size_t)tk * (2 * FDIM) + abase + kg;
        albase[it] = (it * 256 + w * 64) * 8;
    }

    int c = tid & 63;
    int slotW = (w ^ ((c >> 1) & 3)) * 8;
    const float* bp_ = B + (size_t)(w * 8) * DIM + col0 + c;

    float bx[8];
    auto loadB = [&](int k0) {
        const float* pb = bp_ + (size_t)k0 * DIM;
        #pragma unroll
        for (int j = 0; j < 8; ++j) bx[j] = pb[(size_t)j * DIM];
    };
    auto commitB = [&](int p_) {
        unsigned int bw[4];
        #pragma unroll
        for (int j = 0; j < 4; ++j) bw[j] = cvtpk(bx[2*j], bx[2*j+1]);
        *(uint4*)&Bs[p_][c * 32 + slotW] = make_uint4(bw[0], bw[1], bw[2], bw[3]);
    };
    auto loadA = [&](int k0, int p_) {
        #pragma unroll
        for (int it = 0; it < 2; ++it)
            glds16(Hc + agoff[it] + k0, &As[p_][0], albase[it]);
    };

    floatx4 acc[2][4];
    #pragma unroll
    for (int mi = 0; mi < 2; ++mi)
    #pragma unroll
    for (int ni = 0; ni < 4; ++ni) {
        floatx4 z = {0.f, 0.f, 0.f, 0.f};
        acc[mi][ni] = z;
    }

    loadA(0, 0);
    loadB(0);
    commitB(0);
    loadB(32);

    int p = 0;
    for (int k0 = 0; k0 < 1024; k0 += 32) {
        // outstanding at top: stageA(t)[2] + loadB(t+1)[8] -> vmcnt(8)
        asm volatile("s_waitcnt vmcnt(8) lgkmcnt(0)\n\ts_barrier" ::: "memory");
        bool more = (k0 + 32 < 1024);
        if (more) loadA(k0 + 32, p ^ 1);
        __builtin_amdgcn_sched_barrier(0);
        int g = lane >> 4;
        short8 af[2], bf[4];
        #pragma unroll
        for (int mi = 0; mi < 2; ++mi) {
            int r = w * 32 + mi * 16 + (lane & 15);
            int slot = (g ^ ((r >> 1) & 3)) * 8;
            af[mi] = *(const short8*)&As[p][r * 32 + slot];
        }
        #pragma unroll
        for (int ni = 0; ni < 4; ++ni) {
            int n = ni * 16 + (lane & 15);
            int slot = (g ^ ((n >> 1) & 3)) * 8;
            bf[ni] = *(const short8*)&Bs[p][n * 32 + slot];
        }
        if (more) {
            commitB(p ^ 1);
            int nk2 = k0 + 64; if (nk2 >= 1024) nk2 = 0;
            loadB(nk2);
        }
        __builtin_amdgcn_s_setprio(1);
        #pragma unroll
        for (int mi = 0; mi < 2; ++mi)
        #pragma unroll
        for (int ni = 0; ni < 4; ++ni)
            acc[mi][ni] = __builtin_amdgcn_mfma_f32_16x16x32_bf16(af[mi], bf[ni], acc[mi][ni], 0, 0, 0);
        __builtin_amdgcn_s_setprio(0);
        p ^= 1;
    }

    #pragma unroll
    for (int mi = 0; mi < 2; ++mi)
    #pragma unroll
    for (int ni = 0; ni < 4; ++ni)
    #pragma unroll
    for (int r = 0; r < 4; ++r) {
        int row = w * 32 + mi * 16 + (lane >> 4) * 4 + r;
        int tok = toks[row];
        if (tok < 0) continue;
        int col = col0 + ni * 16 + (lane & 15);
        atomicAdd(&out[(size_t)tok * DIM + col], acc[mi][ni][r]);
    }
}

extern "C" void kernel_launch(void* const* d_in, const int* in_sizes, int n_in,
                              void* d_out, int out_size, void* d_ws, size_t ws_size,
                              hipStream_t stream)
{
    const float* h   = (const float*)d_in[0];
    const float* rw  = (const float*)d_in[1];
    const float* wg  = (const float*)d_in[2];
    const float* wu  = (const float*)d_in[3];
    const float* wd  = (const float*)d_in[4];
    const float* wsg = (const float*)d_in[5];
    const float* wsu = (const float*)d_in[6];
    const float* wsd = (const float*)d_in[7];
    float* out = (float*)d_out;

    char* ws = (char*)d_ws;
    int* counts   = (int*)ws;
    int* gu_tiles = (int*)(ws + 256);
    int* dn_tiles = (int*)(ws + 1024);
    int* lists    = (int*)(ws + 2048);                        // 64 KB
    unsigned short* hb = (unsigned short*)(ws + 131072);      // [T][D] bf16, 4 MB
    unsigned short* xb = hb + (size_t)T_TOK * DIM;            // 4 MB
    unsigned short* Hc = xb + (size_t)T_TOK * DIM;            // [T][2F] bf16, 16 MB

    (void)hipMemsetAsync(counts, 0, 64, stream);
    (void)hipMemsetAsync(out, 0, (size_t)T_TOK * DIM * sizeof(float), stream);
    k_router<<<dim3(T_TOK / 4), 256, 0, stream>>>(h, rw, counts, lists, hb, xb);
    k_schedule<<<dim3(1), 64, 0, stream>>>(counts, gu_tiles, dn_tiles);
    k_gateup<<<dim3(FDIM / 64, GU_MAX), 256, 0, stream>>>(
        xb, hb, wg, wu, wsg, wsu, counts, lists, gu_tiles, Hc);
    k_down<<<dim3(DIM / 64, DN_MAX), 256, 0, stream>>>(
        Hc, wd, wsd, counts, lists, dn_tiles, out);
}

// Round 5
// 368.164 us; speedup vs baseline: 1.4865x; 1.0129x over previous
//
#include <hip/hip_runtime.h>
#include <hip/hip_bf16.h>
#include <cstdint>
#include <cstddef>

#define T_TOK 2048
#define DIM   1024
#define FDIM  2048
#define NEXP  8

#define GU_MAX 48   // sum ceil(cnt/128) <= 24 routed + 16 shared
#define DN_MAX 96   // <= 24 routed tiles * 4 K-chunks

typedef short  short8  __attribute__((ext_vector_type(8)));
typedef float  floatx4 __attribute__((ext_vector_type(4)));

__device__ inline unsigned short f2bf(float f) {
    unsigned int u = __builtin_bit_cast(unsigned int, f);
    unsigned int r = (u + 0x7FFFu + ((u >> 16) & 1u)) >> 16;  // RNE
    return (unsigned short)r;
}

// v_cvt_pk_bf16_f32: lo=bf16(a), hi=bf16(b). Hardware RNE on gfx950.
__device__ inline unsigned int cvtpk(float a, float b) {
    unsigned int r;
    asm("v_cvt_pk_bf16_f32 %0, %1, %2" : "=v"(r) : "v"(a), "v"(b));
    return r;
}

// 3-bit bijective XOR key for 128B-stride LDS rows (8 quads/row).
// Used on BOTH the glds16 global-source granule and the ds_read slot
// (rule: both-sides-or-neither). Balanced: any b128 instr with 16
// consecutive rows x 4 octets lands 8 lanes per 16B bank-quad.
__device__ inline int key3(int r) { return ((r >> 1) & 3) | ((r & 1) << 2); }

// async global->LDS 16B/lane; lds base MUST be wave-uniform (HW: base + lane*16)
__device__ inline void glds16(const void* g, const unsigned short* lds_base, int elem_off) {
    int u = __builtin_amdgcn_readfirstlane(elem_off);  // force SGPR: no waterfall
    __builtin_amdgcn_global_load_lds(
        (const __attribute__((address_space(1))) unsigned int*)g,
        (__attribute__((address_space(3))) unsigned int*)(lds_base + u), 16, 0, 0);
}

// ---------------- Kernel: router + bf16 activation prep ----------------
__global__ __launch_bounds__(256) void k_router(
    const float* __restrict__ h, const float* __restrict__ rw,
    int* __restrict__ counts, int* __restrict__ lists,
    unsigned short* __restrict__ hb, unsigned short* __restrict__ xb)
{
    int w = threadIdx.x >> 6, lane = threadIdx.x & 63;
    int t = blockIdx.x * 4 + w;
    const float* hrow = h + (size_t)t * DIM;
    float hv[16];
    #pragma unroll
    for (int i = 0; i < 16; ++i) hv[i] = hrow[lane + 64 * i];
    float acc[NEXP];
    #pragma unroll
    for (int e = 0; e < NEXP; ++e) {
        const float* r = rw + (size_t)e * DIM;
        float s = 0.f;
        #pragma unroll
        for (int i = 0; i < 16; ++i) s += hv[i] * r[lane + 64 * i];
        acc[e] = s;
    }
    #pragma unroll
    for (int e = 0; e < NEXP; ++e) {
        float s = acc[e];
        for (int off = 32; off > 0; off >>= 1) s += __shfl_down(s, off);
        acc[e] = s;
    }
    float score = 0.f;
    if (lane == 0) {
        int be = 0; float bv = acc[0];
        #pragma unroll
        for (int e = 1; e < NEXP; ++e) if (acc[e] > bv) { bv = acc[e]; be = e; }
        score = 1.f / (1.f + __expf(-bv));
        int pos = atomicAdd(&counts[be], 1);
        lists[be * T_TOK + pos] = t;
    }
    score = __shfl(score, 0);
    unsigned short* hbr = hb + (size_t)t * DIM;
    unsigned short* xbr = xb + (size_t)t * DIM;
    #pragma unroll
    for (int i = 0; i < 16; ++i) {
        hbr[lane + 64 * i] = f2bf(hv[i]);
        xbr[lane + 64 * i] = f2bf(score * hv[i]);
    }
}

// ---------------- Kernel: compact tile scheduler (128-row tiles) --------
__global__ void k_schedule(const int* __restrict__ counts,
                           int* __restrict__ gu, int* __restrict__ dn)
{
    if (threadIdx.x != 0 || blockIdx.x != 0) return;
    int n = 0;
    for (int e = 0; e < NEXP; ++e) {
        int c = counts[e];
        for (int r = 0; r < c; r += 128) gu[n++] = (e << 16) | r;
    }
    for (int r = 0; r < T_TOK; r += 128) gu[n++] = (NEXP << 16) | r;
    while (n < GU_MAX) gu[n++] = -1;
    n = 0;
    for (int e = 0; e < NEXP; ++e) {
        int c = counts[e];
        for (int r = 0; r < c; r += 128)
            for (int kc = 0; kc < 4; ++kc)         // (half = kc>>1, chunk = kc&1)
                dn[n++] = (kc << 26) | (e << 16) | r;
    }
    while (n < DN_MAX) dn[n++] = -1;
}

// ---------------- Kernel: fused gate/up GEMM + silu*mul -> Hc ----------
// 128x64 tile, K=1024, BK=64 (16 iters; r4 showed ~2000cy/block-iter of
// latency exposure at BK=32 -> halve events, lengthen covers past ~900cy
// HBM latency). Two K-subphases per iter; commitB after the ks=0 MFMA
// cluster gives the B loads an extra MFMA-phase of cover. Counted vmcnt:
// top wait vmcnt(32) retires the 4 glds16 of tile t while 32 B-prefetch
// loads stay in flight. LDS 64.5KB -> 2 blocks/CU (= r4 measured).
__global__ __launch_bounds__(256, 2) void k_gateup(
    const unsigned short* __restrict__ xb, const unsigned short* __restrict__ hb,
    const float* __restrict__ w_gate, const float* __restrict__ w_up,
    const float* __restrict__ ws_gate, const float* __restrict__ ws_up,
    const int* __restrict__ counts, const int* __restrict__ lists,
    const int* __restrict__ gu_tiles, unsigned short* __restrict__ Hc)
{
    int ent = gu_tiles[blockIdx.y];
    if (ent < 0) return;
    int e = ent >> 16, row0 = ent & 0xffff;
    bool sh = (e == NEXP);
    int cnt = sh ? T_TOK : counts[e];
    const unsigned short* Asrc = sh ? hb : xb;
    const float* Bg = sh ? ws_gate : w_gate + (size_t)e * DIM * FDIM;
    const float* Bu = sh ? ws_up   : w_up   + (size_t)e * DIM * FDIM;
    int outoff = sh ? FDIM : 0;
    int col0 = blockIdx.x * 64;

    __shared__ int toks[128];
    __shared__ __align__(16) unsigned short As [2][128 * 64];
    __shared__ __align__(16) unsigned short Bgs[2][64 * 64];
    __shared__ __align__(16) unsigned short Bus[2][64 * 64];

    int tid = threadIdx.x;
    if (tid < 128) {
        int r = row0 + tid;
        toks[tid] = (r < cnt) ? (sh ? r : lists[e * T_TOK + r]) : -1;
    }
    __syncthreads();

    int lane = tid & 63, w = tid >> 6;

    // A staging: 4 rounds of glds16; global granule key3-swizzled per row
    size_t agoff[4]; int albase[4];
    #pragma unroll
    for (int it = 0; it < 4; ++it) {
        int tt = tid + it * 256;
        int rr = tt >> 3, sq = tt & 7;
        int kg = (sq ^ key3(rr)) * 8;
        int tk = toks[rr]; if (tk < 0) tk = 0;
        agoff[it] = (size_t)tk * DIM + kg;
        albase[it] = (it * 256 + w * 64) * 8;   // wave-uniform short offset
    }

    // B staging: thread owns col c, k-octets {w, w+4} (16 k's per mat).
    int c = tid & 63;
    int sB0 = (w ^ key3(c)) * 8;            // octet w slot; octet w+4 = sB0^32
    const float* bgp = Bg + (size_t)(w * 8) * FDIM + col0 + c;
    const float* bup = Bu + (size_t)(w * 8) * FDIM + col0 + c;

    float gx[16], ux[16];
    auto loadB = [&](int k0) {
        #pragma unroll
        for (int o2 = 0; o2 < 2; ++o2)
        #pragma unroll
        for (int j = 0; j < 8; ++j) {
            size_t off = (size_t)(k0 + o2 * 32 + j) * FDIM;
            gx[o2 * 8 + j] = bgp[off];
            ux[o2 * 8 + j] = bup[off];
        }
    };
    auto commitB = [&](int p_) {
        unsigned int gw[8], uw[8];
        #pragma unroll
        for (int j = 0; j < 8; ++j) {
            gw[j] = cvtpk(gx[2*j], gx[2*j+1]);
            uw[j] = cvtpk(ux[2*j], ux[2*j+1]);
        }
        *(uint4*)&Bgs[p_][c * 64 + sB0]        = make_uint4(gw[0], gw[1], gw[2], gw[3]);
        *(uint4*)&Bgs[p_][c * 64 + (sB0 ^ 32)] = make_uint4(gw[4], gw[5], gw[6], gw[7]);
        *(uint4*)&Bus[p_][c * 64 + sB0]        = make_uint4(uw[0], uw[1], uw[2], uw[3]);
        *(uint4*)&Bus[p_][c * 64 + (sB0 ^ 32)] = make_uint4(uw[4], uw[5], uw[6], uw[7]);
    };
    auto loadA = [&](int k0, int p_) {
        #pragma unroll
        for (int it = 0; it < 4; ++it)
            glds16(Asrc + agoff[it] + k0, &As[p_][0], albase[it]);
    };

    floatx4 accg[2][4], accu[2][4];
    #pragma unroll
    for (int mi = 0; mi < 2; ++mi)
    #pragma unroll
    for (int ni = 0; ni < 4; ++ni) {
        floatx4 z = {0.f, 0.f, 0.f, 0.f};
        accg[mi][ni] = z; accu[mi][ni] = z;
    }

    // prologue: buf0 <- tile 0; regs <- tile 1 (32 loads in flight at loop)
    loadA(0, 0);
    loadB(0);
    commitB(0);      // compiler drains vmcnt: tile0 fully staged
    loadB(64);

    int g = lane >> 4, l15 = lane & 15;
    int p = 0;
    for (int k0 = 0; k0 < DIM; k0 += 64) {
        // outstanding at top: A(t)[4 glds16] + B(t+1)[32] -> vmcnt(32)
        asm volatile("s_waitcnt vmcnt(32) lgkmcnt(0)\n\ts_barrier" ::: "memory");
        bool more = (k0 + 64 < DIM);
        if (more) loadA(k0 + 64, p ^ 1);
        __builtin_amdgcn_sched_barrier(0);   // pin glds16 before later VMEM
        #pragma unroll
        for (int ks = 0; ks < 2; ++ks) {
            short8 af[2], bgf[4], buf_[4];
            int oct = ks * 4 + g;
            #pragma unroll
            for (int mi = 0; mi < 2; ++mi) {
                int r = w * 32 + mi * 16 + l15;
                af[mi] = *(const short8*)&As[p][r * 64 + (oct ^ key3(r)) * 8];
            }
            #pragma unroll
            for (int ni = 0; ni < 4; ++ni) {
                int n = ni * 16 + l15;
                int s = (oct ^ key3(n)) * 8;
                bgf[ni]  = *(const short8*)&Bgs[p][n * 64 + s];
                buf_[ni] = *(const short8*)&Bus[p][n * 64 + s];
            }
            __builtin_amdgcn_s_setprio(1);
            #pragma unroll
            for (int mi = 0; mi < 2; ++mi)
            #pragma unroll
            for (int ni = 0; ni < 4; ++ni) {
                accg[mi][ni] = __builtin_amdgcn_mfma_f32_16x16x32_bf16(af[mi], bgf[ni],  accg[mi][ni], 0, 0, 0);
                accu[mi][ni] = __builtin_amdgcn_mfma_f32_16x16x32_bf16(af[mi], buf_[ni], accu[mi][ni], 0, 0, 0);
            }
            __builtin_amdgcn_s_setprio(0);
            if (ks == 0 && more) {
                commitB(p ^ 1);          // waits vmcnt(4): glds16 keeps flying
                int nk2 = k0 + 128; if (nk2 >= DIM) nk2 = 0;
                loadB(nk2);
            }
        }
        p ^= 1;
    }

    #pragma unroll
    for (int mi = 0; mi < 2; ++mi)
    #pragma unroll
    for (int ni = 0; ni < 4; ++ni)
    #pragma unroll
    for (int r = 0; r < 4; ++r) {
        int row = w * 32 + mi * 16 + (lane >> 4) * 4 + r;
        int tok = toks[row];
        if (tok < 0) continue;
        int col = col0 + ni * 16 + (lane & 15);
        float gv = accg[mi][ni][r], uv = accu[mi][ni][r];
        float hval = (gv / (1.f + __expf(-gv))) * uv;
        Hc[(size_t)tok * (2 * FDIM) + outoff + col] = f2bf(hval);
    }
}

// ---------------- Kernel: fused down-proj, split-K=4, atomic -----------
// 128x64 tile, K-chunk=1024, BK=64 (16 iters); same pipeline.
// LDS 48.5KB -> 3 blocks/CU.
__global__ __launch_bounds__(256, 2) void k_down(
    const unsigned short* __restrict__ Hc,
    const float* __restrict__ w_down, const float* __restrict__ ws_down,
    const int* __restrict__ counts, const int* __restrict__ lists,
    const int* __restrict__ dn_tiles, float* __restrict__ out)
{
    int ent = dn_tiles[blockIdx.y];
    if (ent < 0) return;
    int kc = (ent >> 26) & 3, e = (ent >> 16) & 0xff, row0 = ent & 0xffff;
    int half = kc >> 1, chunk = kc & 1;
    int cnt = counts[e];
    const float* B = (half ? ws_down : w_down + (size_t)e * FDIM * DIM)
                     + (size_t)(chunk * 1024) * DIM;
    int col0 = blockIdx.x * 64;
    size_t abase = (size_t)(half * FDIM + chunk * 1024);

    __shared__ int toks[128];
    __shared__ __align__(16) unsigned short As[2][128 * 64];
    __shared__ __align__(16) unsigned short Bs[2][64 * 64];

    int tid = threadIdx.x;
    if (tid < 128) {
        int r = row0 + tid;
        toks[tid] = (r < cnt) ? lists[e * T_TOK + r] : -1;
    }
    __syncthreads();

    int lane = tid & 63, w = tid >> 6;

    size_t agoff[4]; int albase[4];
    #pragma unroll
    for (int it = 0; it < 4; ++it) {
        int tt = tid + it * 256;
        int rr = tt >> 3, sq = tt & 7;
        int kg = (sq ^ key3(rr)) * 8;
        int tk = toks[rr]; if (tk < 0) tk = 0;
        agoff[it] = (size_t)tk * (2 * FDIM) + abase + kg;
        albase[it] = (it * 256 + w * 64) * 8;
    }

    int c = tid & 63;
    int sB0 = (w ^ key3(c)) * 8;
    const float* bp_ = B + (size_t)(w * 8) * DIM + col0 + c;

    float bx[16];
    auto loadB = [&](int k0) {
        #pragma unroll
        for (int o2 = 0; o2 < 2; ++o2)
        #pragma unroll
        for (int j = 0; j < 8; ++j)
            bx[o2 * 8 + j] = bp_[(size_t)(k0 + o2 * 32 + j) * DIM];
    };
    auto commitB = [&](int p_) {
        unsigned int bw[8];
        #pragma unroll
        for (int j = 0; j < 8; ++j) bw[j] = cvtpk(bx[2*j], bx[2*j+1]);
        *(uint4*)&Bs[p_][c * 64 + sB0]        = make_uint4(bw[0], bw[1], bw[2], bw[3]);
        *(uint4*)&Bs[p_][c * 64 + (sB0 ^ 32)] = make_uint4(bw[4], bw[5], bw[6], bw[7]);
    };
    auto loadA = [&](int k0, int p_) {
        #pragma unroll
        for (int it = 0; it < 4; ++it)
            glds16(Hc + agoff[it] + k0, &As[p_][0], albase[it]);
    };

    floatx4 acc[2][4];
    #pragma unroll
    for (int mi = 0; mi < 2; ++mi)
    #pragma unroll
    for (int ni = 0; ni < 4; ++ni) {
        floatx4 z = {0.f, 0.f, 0.f, 0.f};
        acc[mi][ni] = z;
    }

    loadA(0, 0);
    loadB(0);
    commitB(0);
    loadB(64);

    int g = lane >> 4, l15 = lane & 15;
    int p = 0;
    for (int k0 = 0; k0 < 1024; k0 += 64) {
        // outstanding at top: A(t)[4] + B(t+1)[16] -> vmcnt(16)
        asm volatile("s_waitcnt vmcnt(16) lgkmcnt(0)\n\ts_barrier" ::: "memory");
        bool more = (k0 + 64 < 1024);
        if (more) loadA(k0 + 64, p ^ 1);
        __builtin_amdgcn_sched_barrier(0);
        #pragma unroll
        for (int ks = 0; ks < 2; ++ks) {
            short8 af[2], bf[4];
            int oct = ks * 4 + g;
            #pragma unroll
            for (int mi = 0; mi < 2; ++mi) {
                int r = w * 32 + mi * 16 + l15;
                af[mi] = *(const short8*)&As[p][r * 64 + (oct ^ key3(r)) * 8];
            }
            #pragma unroll
            for (int ni = 0; ni < 4; ++ni) {
                int n = ni * 16 + l15;
                bf[ni] = *(const short8*)&Bs[p][n * 64 + (oct ^ key3(n)) * 8];
            }
            __builtin_amdgcn_s_setprio(1);
            #pragma unroll
            for (int mi = 0; mi < 2; ++mi)
            #pragma unroll
            for (int ni = 0; ni < 4; ++ni)
                acc[mi][ni] = __builtin_amdgcn_mfma_f32_16x16x32_bf16(af[mi], bf[ni], acc[mi][ni], 0, 0, 0);
            __builtin_amdgcn_s_setprio(0);
            if (ks == 0 && more) {
                commitB(p ^ 1);
                int nk2 = k0 + 128; if (nk2 >= 1024) nk2 = 0;
                loadB(nk2);
            }
        }
        p ^= 1;
    }

    #pragma unroll
    for (int mi = 0; mi < 2; ++mi)
    #pragma unroll
    for (int ni = 0; ni < 4; ++ni)
    #pragma unroll
    for (int r = 0; r < 4; ++r) {
        int row = w * 32 + mi * 16 + (lane >> 4) * 4 + r;
        int tok = toks[row];
        if (tok < 0) continue;
        int col = col0 + ni * 16 + (lane & 15);
        atomicAdd(&out[(size_t)tok * DIM + col], acc[mi][ni][r]);
    }
}

extern "C" void kernel_launch(void* const* d_in, const int* in_sizes, int n_in,
                              void* d_out, int out_size, void* d_ws, size_t ws_size,
                              hipStream_t stream)
{
    const float* h   = (const float*)d_in[0];
    const float* rw  = (const float*)d_in[1];
    const float* wg  = (const float*)d_in[2];
    const float* wu  = (const float*)d_in[3];
    const float* wd  = (const float*)d_in[4];
    const float* wsg = (const float*)d_in[5];
    const float* wsu = (const float*)d_in[6];
    const float* wsd = (const float*)d_in[7];
    float* out = (float*)d_out;

    char* ws = (char*)d_ws;
    int* counts   = (int*)ws;
    int* gu_tiles = (int*)(ws + 256);
    int* dn_tiles = (int*)(ws + 1024);
    int* lists    = (int*)(ws + 2048);                        // 64 KB
    unsigned short* hb = (unsigned short*)(ws + 131072);      // [T][D] bf16, 4 MB
    unsigned short* xb = hb + (size_t)T_TOK * DIM;            // 4 MB
    unsigned short* Hc = xb + (size_t)T_TOK * DIM;            // [T][2F] bf16, 16 MB

    (void)hipMemsetAsync(counts, 0, 64, stream);
    (void)hipMemsetAsync(out, 0, (size_t)T_TOK * DIM * sizeof(float), stream);
    k_router<<<dim3(T_TOK / 4), 256, 0, stream>>>(h, rw, counts, lists, hb, xb);
    k_schedule<<<dim3(1), 64, 0, stream>>>(counts, gu_tiles, dn_tiles);
    k_gateup<<<dim3(FDIM / 64, GU_MAX), 256, 0, stream>>>(
        xb, hb, wg, wu, wsg, wsu, counts, lists, gu_tiles, Hc);
    k_down<<<dim3(DIM / 64, DN_MAX), 256, 0, stream>>>(
        Hc, wd, wsd, counts, lists, dn_tiles, out);
}